// Round 1
// baseline (9579.089 us; speedup 1.0000x reference)
//
#include <hip/hip_runtime.h>

#define B_    32
#define SSRC  128
#define STGT  64
#define E_    256
#define H_    512
#define G4    2048
#define V_    32000

typedef unsigned short u16;
typedef short bf16x8 __attribute__((ext_vector_type(8)));
typedef float f32x4 __attribute__((ext_vector_type(4)));

__device__ __forceinline__ u16 f2b(float f) {
  unsigned u = __float_as_uint(f);
  u += 0x7FFFu + ((u >> 16) & 1u);
  return (u16)(u >> 16);
}
__device__ __forceinline__ float b2f(u16 h) {
  return __uint_as_float(((unsigned)h) << 16);
}
__device__ __forceinline__ float sigm(float x) { return 1.0f / (1.0f + __expf(-x)); }
__device__ __forceinline__ float tanh_(float x) { return 1.0f - 2.0f / (1.0f + __expf(2.0f * x)); }

// ---------------- group barrier (32 blocks, sense via generation counter) --------
__device__ __forceinline__ void gbar(int* cnt, int* gen) {
  __syncthreads();
  if (threadIdx.x == 0) {
    __threadfence();
    int g0 = __hip_atomic_load(gen, __ATOMIC_RELAXED, __HIP_MEMORY_SCOPE_AGENT);
    int a = __hip_atomic_fetch_add(cnt, 1, __ATOMIC_ACQ_REL, __HIP_MEMORY_SCOPE_AGENT);
    if (a == 31) {
      __hip_atomic_store(cnt, 0, __ATOMIC_RELAXED, __HIP_MEMORY_SCOPE_AGENT);
      __hip_atomic_store(gen, g0 + 1, __ATOMIC_RELEASE, __HIP_MEMORY_SCOPE_AGENT);
    } else {
      int cur;
      do {
        __builtin_amdgcn_s_sleep(2);
        cur = __hip_atomic_load(gen, __ATOMIC_ACQUIRE, __HIP_MEMORY_SCOPE_AGENT);
      } while (cur == g0);
    }
  }
  __syncthreads();
}

// ---------------- prep: gathers + bf16 conversions ----------------
__global__ void prep_kernel(const int* __restrict__ src, const int* __restrict__ tgt,
                            const float* __restrict__ enc_emb, const float* __restrict__ dec_emb,
                            const float* __restrict__ enc_Wih, const float* __restrict__ dec_Wih,
                            const float* __restrict__ out_W,
                            u16* __restrict__ A_enc, u16* __restrict__ A_dec,
                            u16* __restrict__ WihE, u16* __restrict__ WihD,
                            u16* __restrict__ outWb)
{
  const long n_outw = (long)V_ * H_;
  const long n_aenc = (long)B_ * SSRC * E_;
  const long n_adec = (long)B_ * STGT * E_;
  const long n_wih  = (long)G4 * E_;
  const long total = n_outw + n_aenc + n_adec + n_wih + n_wih;
  for (long i = (long)blockIdx.x * blockDim.x + threadIdx.x; i < total;
       i += (long)gridDim.x * blockDim.x) {
    long x = i;
    if (x < n_outw) { outWb[x] = f2b(out_W[x]); continue; }
    x -= n_outw;
    if (x < n_aenc) {
      int row = (int)(x >> 8), e = (int)(x & 255);
      A_enc[x] = f2b(enc_emb[(size_t)src[row] * E_ + e]);
      continue;
    }
    x -= n_aenc;
    if (x < n_adec) {
      int row = (int)(x >> 8), e = (int)(x & 255);
      A_dec[x] = f2b(dec_emb[(size_t)tgt[row] * E_ + e]);
      continue;
    }
    x -= n_adec;
    if (x < n_wih) { WihE[x] = f2b(enc_Wih[x]); continue; }
    x -= n_wih;
    {
      int r = (int)(x >> 8), e = (int)(x & 255);
      WihD[x] = f2b(dec_Wih[(size_t)r * 768 + e]);
    }
  }
}

// ---------------- NT GEMM: C[m][n] = sum_k A[m][k]*B[n][k] + bias[n] ----------------
// A: M x K bf16 row-major, B: N x K bf16 row-major. M%128==0, N%128==0, K%32==0.
template<int KTOT, bool OBF>
__global__ __launch_bounds__(256, 2) void gemm_nt(
    const u16* __restrict__ A, const u16* __restrict__ Bm,
    const float* __restrict__ bias, void* __restrict__ Cv, int M, int N)
{
  int nbm = M >> 7;
  int bn = blockIdx.x / nbm;
  int bm = blockIdx.x % nbm;
  int w = threadIdx.x >> 6, l = threadIdx.x & 63;
  int wr = w >> 1, wc = w & 1;
  int m0 = bm * 128 + wr * 64, n0 = bn * 128 + wc * 64;
  int lr = l & 15, ko = (l >> 4) * 8;
  f32x4 acc[4][4] = {};
  const u16* Ap = A + (size_t)(m0 + lr) * KTOT + ko;
  const u16* Bp = Bm + (size_t)(n0 + lr) * KTOT + ko;
  for (int k0 = 0; k0 < KTOT; k0 += 32) {
    bf16x8 af[4], bfr[4];
#pragma unroll
    for (int i = 0; i < 4; ++i) af[i] = *(const bf16x8*)(Ap + (size_t)i * 16 * KTOT + k0);
#pragma unroll
    for (int i = 0; i < 4; ++i) bfr[i] = *(const bf16x8*)(Bp + (size_t)i * 16 * KTOT + k0);
#pragma unroll
    for (int i = 0; i < 4; ++i)
#pragma unroll
      for (int j = 0; j < 4; ++j)
        acc[i][j] = __builtin_amdgcn_mfma_f32_16x16x32_bf16(af[i], bfr[j], acc[i][j], 0, 0, 0);
  }
  int rbase = (l >> 4) * 4;
#pragma unroll
  for (int i = 0; i < 4; ++i) {
#pragma unroll
    for (int j = 0; j < 4; ++j) {
      int gn = n0 + j * 16 + lr;
      float bv = bias[gn];
#pragma unroll
      for (int r = 0; r < 4; ++r) {
        int gm = m0 + i * 16 + rbase + r;
        float v = acc[i][j][r] + bv;
        if (OBF) ((u16*)Cv)[(size_t)gm * N + gn] = f2b(v);
        else     ((float*)Cv)[(size_t)gm * N + gn] = v;
      }
    }
  }
}

// ---------------- enc_proj sub-phase (uses h staged in LDS) ----------------
__device__ __forceinline__ void enc_proj_phase(
    int tid, int gb, int b0, int tt,
    float (*hl)[H_], float (*part)[256],
    const float* __restrict__ attn_W, float* __restrict__ enc_proj)
{
  int b_l = tid >> 6, d_l = (tid >> 2) & 15, kq = tid & 3;
  int d = gb * 16 + d_l;
  const float* wrow = attn_W + (size_t)d * 1024 + 512;  // W_e row
  float acc = 0.f;
#pragma unroll 8
  for (int kk = kq * 128; kk < kq * 128 + 128; kk += 4) {
    float4 wv = *(const float4*)(wrow + kk);
    const float* hp = &hl[b_l][kk];
    acc += wv.x * hp[0] + wv.y * hp[1] + wv.z * hp[2] + wv.w * hp[3];
  }
  part[kq][b_l * 16 + d_l] = acc;
  __syncthreads();
  if (tid < 64) {
    int bl = tid >> 4, dl = tid & 15;
    float s = part[0][bl * 16 + dl] + part[1][bl * 16 + dl] +
              part[2][bl * 16 + dl] + part[3][bl * 16 + dl];
    enc_proj[((size_t)(b0 + bl) * SSRC + tt) * H_ + gb * 16 + dl] = s;
  }
  __syncthreads();
}

// ---------------- persistent recurrence kernel ----------------
// 256 blocks x 256 threads. Group g = blockIdx&7 (32 blocks, 4 batch rows), gb = blockIdx>>3.
__global__ __launch_bounds__(256, 1) void seq_recurrent(
    const float* __restrict__ enc_Whh, const float* __restrict__ attn_W,
    const float* __restrict__ attn_b, const float* __restrict__ attn_v,
    const float* __restrict__ dec_Whh, const float* __restrict__ dec_Wih,
    const u16* __restrict__ encXW, const u16* __restrict__ decXW,
    float* __restrict__ hbuf, float* __restrict__ cbuf,
    float* __restrict__ qbuf, float* __restrict__ ctxbuf, float* __restrict__ scorebuf,
    u16* __restrict__ enc_out_bf, float* __restrict__ enc_proj, u16* __restrict__ dec_h_bf,
    int* __restrict__ bars)
{
  const int tid = threadIdx.x;
  const int blk = blockIdx.x;
  const int g = blk & 7;
  const int gb = blk >> 3;
  const int b0 = g * 4;
  int* cnt = bars + g * 64;
  int* gen = cnt + 16;

  __shared__ union {
    float encW[64 * 512];        // f32 [k4][row64][4]
    u16   decW[2][64 * 512];     // bf16 [k8][row64][8], [0]=Whh slice, [1]=Wih_ctx slice
  } W;
  __shared__ float part[4][256];
  __shared__ float zx[4][64];
  __shared__ float smx[4][128];
  __shared__ float red[16][16];
  __shared__ float hl[4][H_];
  __shared__ float cxl[4][H_];

  // ---- fill encoder Whh slice (f32) ----
  for (int idx = tid; idx < 64 * 512; idx += 256) {
    int row_l = idx >> 9, kk = idx & 511;
    int grow = (row_l >> 4) * 512 + gb * 16 + (row_l & 15);
    W.encW[(kk >> 2) * 256 + row_l * 4 + (kk & 3)] = enc_Whh[(size_t)grow * 512 + kk];
  }
  __syncthreads();

  // =================== ENCODER ===================
  for (int t = 0; t < SSRC; ++t) {
    const float* hr = hbuf + (t & 1) * (B_ * H_);
    float* hw = hbuf + ((t + 1) & 1) * (B_ * H_);

    // stage h (4 rows) into LDS
    {
      float4* dst = (float4*)&hl[0][0];
      const float4* srcp = (const float4*)(hr + (size_t)b0 * H_);
      for (int i = tid; i < 512; i += 256) dst[i] = srcp[i];
    }
    __syncthreads();

    if (t > 0) enc_proj_phase(tid, gb, b0, t - 1, hl, part, attn_W, enc_proj);

    // z = encXW + h @ Whh^T  (block owns 16 j x 4 gates = 64 rows, all 4 b)
    {
      int rl = tid & 63, kq = tid >> 6;
      float acc0 = 0.f, acc1 = 0.f, acc2 = 0.f, acc3 = 0.f;
      int c0 = kq * 32;
#pragma unroll 4
      for (int c = 0; c < 32; ++c) {
        int k4 = c0 + c;
        float4 wv = *(const float4*)&W.encW[k4 * 256 + rl * 4];
        const float* h0p = &hl[0][k4 * 4];
        const float* h1p = &hl[1][k4 * 4];
        const float* h2p = &hl[2][k4 * 4];
        const float* h3p = &hl[3][k4 * 4];
        acc0 += wv.x * h0p[0] + wv.y * h0p[1] + wv.z * h0p[2] + wv.w * h0p[3];
        acc1 += wv.x * h1p[0] + wv.y * h1p[1] + wv.z * h1p[2] + wv.w * h1p[3];
        acc2 += wv.x * h2p[0] + wv.y * h2p[1] + wv.z * h2p[2] + wv.w * h2p[3];
        acc3 += wv.x * h3p[0] + wv.y * h3p[1] + wv.z * h3p[2] + wv.w * h3p[3];
      }
      part[kq][0 * 64 + rl] = acc0;
      part[kq][1 * 64 + rl] = acc1;
      part[kq][2 * 64 + rl] = acc2;
      part[kq][3 * 64 + rl] = acc3;
      __syncthreads();
      {
        int b_l = tid >> 6, rl2 = tid & 63;
        float z = part[0][b_l * 64 + rl2] + part[1][b_l * 64 + rl2] +
                  part[2][b_l * 64 + rl2] + part[3][b_l * 64 + rl2];
        int grow = (rl2 >> 4) * 512 + gb * 16 + (rl2 & 15);
        z += b2f(encXW[((size_t)(b0 + b_l) * SSRC + t) * G4 + grow]);
        zx[b_l][rl2] = z;
      }
      __syncthreads();
      if (tid < 64) {
        int bl = tid >> 4, jl = tid & 15;
        int b = b0 + bl, j = gb * 16 + jl;
        float iv = zx[bl][jl], fv = zx[bl][16 + jl], gv = zx[bl][32 + jl], ov = zx[bl][48 + jl];
        float co = cbuf[(size_t)b * H_ + j];
        float cn = sigm(fv) * co + sigm(iv) * tanh_(gv);
        float hn = sigm(ov) * tanh_(cn);
        cbuf[(size_t)b * H_ + j] = cn;
        hw[(size_t)b * H_ + j] = hn;
        enc_out_bf[((size_t)b * SSRC + t) * H_ + j] = f2b(hn);
      }
    }
    gbar(cnt, gen);
  }

  // tail: enc_proj for t = 127 (h_127 lives in buffer (SSRC&1)==0)
  {
    const float* hr = hbuf + (SSRC & 1) * (B_ * H_);
    float4* dst = (float4*)&hl[0][0];
    const float4* srcp = (const float4*)(hr + (size_t)b0 * H_);
    for (int i = tid; i < 512; i += 256) dst[i] = srcp[i];
    __syncthreads();
    enc_proj_phase(tid, gb, b0, SSRC - 1, hl, part, attn_W, enc_proj);
  }

  // ---- refill LDS with decoder weight slices (bf16) ----
  __syncthreads();
  for (int idx = tid; idx < 64 * 512; idx += 256) {
    int row_l = idx >> 9, kk = idx & 511;
    int grow = (row_l >> 4) * 512 + gb * 16 + (row_l & 15);
    W.decW[0][(kk >> 3) * 512 + row_l * 8 + (kk & 7)] = f2b(dec_Whh[(size_t)grow * 512 + kk]);
    W.decW[1][(kk >> 3) * 512 + row_l * 8 + (kk & 7)] = f2b(dec_Wih[(size_t)grow * 768 + 256 + kk]);
  }
  __syncthreads();

  // =================== DECODER ===================
  for (int t = 0; t < STGT; ++t) {
    const float* hr = hbuf + ((SSRC + t) & 1) * (B_ * H_);
    float* hw = hbuf + ((SSRC + t + 1) & 1) * (B_ * H_);

    // Phase A: q = h @ W_h^T + attn_b
    {
      float4* dst = (float4*)&hl[0][0];
      const float4* srcp = (const float4*)(hr + (size_t)b0 * H_);
      for (int i = tid; i < 512; i += 256) dst[i] = srcp[i];
      __syncthreads();
      int b_l = tid >> 6, d_l = (tid >> 2) & 15, kq = tid & 3;
      int d = gb * 16 + d_l;
      const float* wrow = attn_W + (size_t)d * 1024;  // W_h row
      float acc = 0.f;
#pragma unroll 8
      for (int kk = kq * 128; kk < kq * 128 + 128; kk += 4) {
        float4 wv = *(const float4*)(wrow + kk);
        const float* hp = &hl[b_l][kk];
        acc += wv.x * hp[0] + wv.y * hp[1] + wv.z * hp[2] + wv.w * hp[3];
      }
      part[kq][b_l * 16 + d_l] = acc;
      __syncthreads();
      if (tid < 64) {
        int bl = tid >> 4, dl = tid & 15;
        float s = part[0][bl * 16 + dl] + part[1][bl * 16 + dl] +
                  part[2][bl * 16 + dl] + part[3][bl * 16 + dl] + attn_b[gb * 16 + dl];
        qbuf[(size_t)(b0 + bl) * H_ + gb * 16 + dl] = s;
      }
    }
    gbar(cnt, gen);

    // Phase B: scores (block owns 4 s values)
    {
      int b_l = tid >> 6, s_l = (tid >> 4) & 3, k16 = tid & 15;
      int b = b0 + b_l, s = gb * 4 + s_l;
      const float* ep = enc_proj + ((size_t)b * SSRC + s) * H_;
      const float* qp = qbuf + (size_t)b * H_;
      float acc = 0.f;
      for (int kk = k16 * 32; kk < k16 * 32 + 32; ++kk)
        acc += attn_v[kk] * tanh_(ep[kk] + qp[kk]);
      red[k16][b_l * 4 + s_l] = acc;
      __syncthreads();
      if (tid < 16) {
        int bl = tid >> 2, sl = tid & 3;
        float s2 = 0.f;
#pragma unroll
        for (int i = 0; i < 16; ++i) s2 += red[i][bl * 4 + sl];
        scorebuf[(size_t)(b0 + bl) * SSRC + gb * 4 + sl] = s2;
      }
    }
    gbar(cnt, gen);

    // Phase C: softmax (per-wave, per-b) + context (block owns 16 d)
    {
      int w = tid >> 6, lane = tid & 63;
      {
        const float* sp = scorebuf + (size_t)(b0 + w) * SSRC;
        float s1 = sp[lane], s2v = sp[64 + lane];
        float m = fmaxf(s1, s2v);
        for (int off = 32; off; off >>= 1) m = fmaxf(m, __shfl_xor(m, off));
        float e1 = __expf(s1 - m), e2 = __expf(s2v - m);
        float sm = e1 + e2;
        for (int off = 32; off; off >>= 1) sm += __shfl_xor(sm, off);
        float inv = 1.0f / sm;
        smx[w][lane] = e1 * inv;
        smx[w][64 + lane] = e2 * inv;
      }
      __syncthreads();
      int b_l = tid >> 6, d_l = (tid >> 2) & 15, sq = tid & 3;
      int b = b0 + b_l, d = gb * 16 + d_l;
      const u16* eo = enc_out_bf + (size_t)b * SSRC * H_ + d;
      float acc = 0.f;
      for (int s = sq * 32; s < sq * 32 + 32; ++s)
        acc += smx[b_l][s] * b2f(eo[(size_t)s * H_]);
      part[sq][b_l * 16 + d_l] = acc;
      __syncthreads();
      if (tid < 64) {
        int bl = tid >> 4, dl = tid & 15;
        float s = part[0][bl * 16 + dl] + part[1][bl * 16 + dl] +
                  part[2][bl * 16 + dl] + part[3][bl * 16 + dl];
        ctxbuf[(size_t)(b0 + bl) * H_ + gb * 16 + dl] = s;
      }
    }
    gbar(cnt, gen);

    // Phase D: z = decXW + h @ Whh^T + ctx @ WihC^T, gates, h/c update
    {
      {
        float4* dst = (float4*)&cxl[0][0];
        const float4* srcp = (const float4*)(ctxbuf + (size_t)b0 * H_);
        for (int i = tid; i < 512; i += 256) dst[i] = srcp[i];
      }
      __syncthreads();
      int rl = tid & 63, kq = tid >> 6;
      float acc[4] = {0.f, 0.f, 0.f, 0.f};
#pragma unroll 2
      for (int c = 0; c < 16; ++c) {
        int k8 = kq * 16 + c;
        bf16x8 wv = *(const bf16x8*)&W.decW[0][k8 * 512 + rl * 8];
        float wf0 = b2f((u16)wv[0]), wf1 = b2f((u16)wv[1]), wf2 = b2f((u16)wv[2]), wf3 = b2f((u16)wv[3]);
        float wf4 = b2f((u16)wv[4]), wf5 = b2f((u16)wv[5]), wf6 = b2f((u16)wv[6]), wf7 = b2f((u16)wv[7]);
#pragma unroll
        for (int bl = 0; bl < 4; ++bl) {
          const float* hp = &hl[bl][k8 * 8];
          acc[bl] += wf0 * hp[0] + wf1 * hp[1] + wf2 * hp[2] + wf3 * hp[3] +
                     wf4 * hp[4] + wf5 * hp[5] + wf6 * hp[6] + wf7 * hp[7];
        }
      }
#pragma unroll 2
      for (int c = 0; c < 16; ++c) {
        int k8 = kq * 16 + c;
        bf16x8 wv = *(const bf16x8*)&W.decW[1][k8 * 512 + rl * 8];
        float wf0 = b2f((u16)wv[0]), wf1 = b2f((u16)wv[1]), wf2 = b2f((u16)wv[2]), wf3 = b2f((u16)wv[3]);
        float wf4 = b2f((u16)wv[4]), wf5 = b2f((u16)wv[5]), wf6 = b2f((u16)wv[6]), wf7 = b2f((u16)wv[7]);
#pragma unroll
        for (int bl = 0; bl < 4; ++bl) {
          const float* cp = &cxl[bl][k8 * 8];
          acc[bl] += wf0 * cp[0] + wf1 * cp[1] + wf2 * cp[2] + wf3 * cp[3] +
                     wf4 * cp[4] + wf5 * cp[5] + wf6 * cp[6] + wf7 * cp[7];
        }
      }
      part[kq][0 * 64 + rl] = acc[0];
      part[kq][1 * 64 + rl] = acc[1];
      part[kq][2 * 64 + rl] = acc[2];
      part[kq][3 * 64 + rl] = acc[3];
      __syncthreads();
      {
        int b_l = tid >> 6, rl2 = tid & 63;
        float z = part[0][b_l * 64 + rl2] + part[1][b_l * 64 + rl2] +
                  part[2][b_l * 64 + rl2] + part[3][b_l * 64 + rl2];
        int grow = (rl2 >> 4) * 512 + gb * 16 + (rl2 & 15);
        z += b2f(decXW[((size_t)(b0 + b_l) * STGT + t) * G4 + grow]);
        zx[b_l][rl2] = z;
      }
      __syncthreads();
      if (tid < 64) {
        int bl = tid >> 4, jl = tid & 15;
        int b = b0 + bl, j = gb * 16 + jl;
        float iv = zx[bl][jl], fv = zx[bl][16 + jl], gv = zx[bl][32 + jl], ov = zx[bl][48 + jl];
        float co = cbuf[(size_t)b * H_ + j];
        float cn = sigm(fv) * co + sigm(iv) * tanh_(gv);
        float hn = sigm(ov) * tanh_(cn);
        cbuf[(size_t)b * H_ + j] = cn;
        hw[(size_t)b * H_ + j] = hn;
        dec_h_bf[((size_t)b * STGT + t) * H_ + j] = f2b(hn);
      }
    }
    gbar(cnt, gen);
  }
}

// ---------------- workspace layout (bytes) ----------------
#define OFF_BAR    0u
#define OFF_H      4096u
#define OFF_C      135168u
#define OFF_Q      200704u
#define OFF_CTX    266240u
#define OFF_SC     331776u
#define OFF_AENC   524288u
#define OFF_ADEC   2621440u
#define OFF_WIHE   3670016u
#define OFF_WIHD   4718592u
#define OFF_OUTW   5767168u
#define OFF_ENCXW  38535168u
#define OFF_DECXW  55312384u
#define OFF_EOBF   63700992u
#define OFF_EPROJ  67895296u
#define OFF_DECH   76283904u

extern "C" void kernel_launch(void* const* d_in, const int* in_sizes, int n_in,
                              void* d_out, int out_size, void* d_ws, size_t ws_size,
                              hipStream_t stream)
{
  const int*   src     = (const int*)d_in[0];
  const int*   tgt     = (const int*)d_in[1];
  const float* enc_emb = (const float*)d_in[2];
  const float* enc_Wih = (const float*)d_in[3];
  const float* enc_Whh = (const float*)d_in[4];
  const float* enc_b   = (const float*)d_in[5];
  const float* attn_W  = (const float*)d_in[6];
  const float* attn_b  = (const float*)d_in[7];
  const float* attn_v  = (const float*)d_in[8];
  const float* dec_emb = (const float*)d_in[9];
  const float* dec_Wih = (const float*)d_in[10];
  const float* dec_Whh = (const float*)d_in[11];
  const float* dec_b   = (const float*)d_in[12];
  const float* out_W   = (const float*)d_in[13];
  const float* out_b   = (const float*)d_in[14];

  char* ws = (char*)d_ws;
  int*   bars    = (int*)(ws + OFF_BAR);
  float* hbuf    = (float*)(ws + OFF_H);
  float* cbuf    = (float*)(ws + OFF_C);
  float* qbuf    = (float*)(ws + OFF_Q);
  float* ctxbuf  = (float*)(ws + OFF_CTX);
  float* scoreb  = (float*)(ws + OFF_SC);
  u16*   A_enc   = (u16*)(ws + OFF_AENC);
  u16*   A_dec   = (u16*)(ws + OFF_ADEC);
  u16*   WihE    = (u16*)(ws + OFF_WIHE);
  u16*   WihD    = (u16*)(ws + OFF_WIHD);
  u16*   outWb   = (u16*)(ws + OFF_OUTW);
  u16*   encXW   = (u16*)(ws + OFF_ENCXW);
  u16*   decXW   = (u16*)(ws + OFF_DECXW);
  u16*   eobf    = (u16*)(ws + OFF_EOBF);
  float* eproj   = (float*)(ws + OFF_EPROJ);
  u16*   dech    = (u16*)(ws + OFF_DECH);

  // zero barriers + h + c (rest is fully written before read)
  hipMemsetAsync(d_ws, 0, OFF_SC + 16384, stream);

  prep_kernel<<<2048, 256, 0, stream>>>(src, tgt, enc_emb, dec_emb, enc_Wih, dec_Wih, out_W,
                                        A_enc, A_dec, WihE, WihD, outWb);

  // encXW = emb_src @ enc_Wih^T + enc_b   (M=4096, N=2048, K=256) -> bf16
  gemm_nt<256, true><<<512, 256, 0, stream>>>(A_enc, WihE, enc_b, (void*)encXW, 4096, 2048);
  // decXW = emb_tgt @ dec_Wih[:, :E]^T + dec_b  (M=2048, N=2048, K=256) -> bf16
  gemm_nt<256, true><<<256, 256, 0, stream>>>(A_dec, WihD, dec_b, (void*)decXW, 2048, 2048);

  seq_recurrent<<<256, 256, 0, stream>>>(enc_Whh, attn_W, attn_b, attn_v, dec_Whh, dec_Wih,
                                         encXW, decXW, hbuf, cbuf, qbuf, ctxbuf, scoreb,
                                         eobf, eproj, dech, bars);

  // out = dec_h @ out_W^T + out_b  (M=2048, N=32000, K=512) -> f32
  gemm_nt<512, false><<<4000, 256, 0, stream>>>(dech, outWb, out_b, d_out, 2048, 32000);
}

// Round 2
// 5529.528 us; speedup vs baseline: 1.7324x; 1.7324x over previous
//
#include <hip/hip_runtime.h>

#define B_    32
#define SSRC  128
#define STGT  64
#define E_    256
#define H_    512
#define G4    2048
#define V_    32000

typedef unsigned short u16;
typedef short bf16x8 __attribute__((ext_vector_type(8)));
typedef float f32x4 __attribute__((ext_vector_type(4)));

__device__ __forceinline__ u16 f2b(float f) {
  unsigned u = __float_as_uint(f);
  u += 0x7FFFu + ((u >> 16) & 1u);
  return (u16)(u >> 16);
}
__device__ __forceinline__ float b2f(u16 h) {
  return __uint_as_float(((unsigned)h) << 16);
}
__device__ __forceinline__ float sigm(float x) { return 1.0f / (1.0f + __expf(-x)); }
__device__ __forceinline__ float tanh_(float x) { return 1.0f - 2.0f / (1.0f + __expf(2.0f * x)); }

// ---------------- group barrier: per-block flag + gang poll (no RMW) ----------
// flags: 32 ints for this group. Arrival: release-store own flag = target.
// Wait: wave 0 polls all 32 flags (coalesced) until all >= target. Targets are
// monotonically increasing epochs -> no reset needed, no reset race.
__device__ __forceinline__ void gbar(int* flags, int myid, int target) {
  __syncthreads();
  if (threadIdx.x < 64) {
    if (threadIdx.x == 0) {
      __threadfence();  // make this block's global writes visible device-wide
      __hip_atomic_store(flags + myid, target, __ATOMIC_RELAXED, __HIP_MEMORY_SCOPE_AGENT);
    }
    int l = threadIdx.x & 31;
    while (__hip_atomic_load(flags + l, __ATOMIC_RELAXED, __HIP_MEMORY_SCOPE_AGENT) < target) {
      __builtin_amdgcn_s_sleep(2);
    }
    __threadfence();  // acquire side: invalidate stale cached lines
  }
  __syncthreads();
}

// ---------------- prep: gathers + bf16 conversions ----------------
__global__ void prep_kernel(const int* __restrict__ src, const int* __restrict__ tgt,
                            const float* __restrict__ enc_emb, const float* __restrict__ dec_emb,
                            const float* __restrict__ enc_Wih, const float* __restrict__ dec_Wih,
                            const float* __restrict__ out_W,
                            u16* __restrict__ A_enc, u16* __restrict__ A_dec,
                            u16* __restrict__ WihE, u16* __restrict__ WihD,
                            u16* __restrict__ outWb)
{
  const long n_outw = (long)V_ * H_;
  const long n_aenc = (long)B_ * SSRC * E_;
  const long n_adec = (long)B_ * STGT * E_;
  const long n_wih  = (long)G4 * E_;
  const long total = n_outw + n_aenc + n_adec + n_wih + n_wih;
  for (long i = (long)blockIdx.x * blockDim.x + threadIdx.x; i < total;
       i += (long)gridDim.x * blockDim.x) {
    long x = i;
    if (x < n_outw) { outWb[x] = f2b(out_W[x]); continue; }
    x -= n_outw;
    if (x < n_aenc) {
      int row = (int)(x >> 8), e = (int)(x & 255);
      A_enc[x] = f2b(enc_emb[(size_t)src[row] * E_ + e]);
      continue;
    }
    x -= n_aenc;
    if (x < n_adec) {
      int row = (int)(x >> 8), e = (int)(x & 255);
      A_dec[x] = f2b(dec_emb[(size_t)tgt[row] * E_ + e]);
      continue;
    }
    x -= n_adec;
    if (x < n_wih) { WihE[x] = f2b(enc_Wih[x]); continue; }
    x -= n_wih;
    {
      int r = (int)(x >> 8), e = (int)(x & 255);
      WihD[x] = f2b(dec_Wih[(size_t)r * 768 + e]);
    }
  }
}

// ---------------- NT GEMM: C[m][n] = sum_k A[m][k]*B[n][k] + bias[n] ----------------
template<int KTOT, bool OBF>
__global__ __launch_bounds__(256, 2) void gemm_nt(
    const u16* __restrict__ A, const u16* __restrict__ Bm,
    const float* __restrict__ bias, void* __restrict__ Cv, int M, int N)
{
  int nbm = M >> 7;
  int bn = blockIdx.x / nbm;
  int bm = blockIdx.x % nbm;
  int w = threadIdx.x >> 6, l = threadIdx.x & 63;
  int wr = w >> 1, wc = w & 1;
  int m0 = bm * 128 + wr * 64, n0 = bn * 128 + wc * 64;
  int lr = l & 15, ko = (l >> 4) * 8;
  f32x4 acc[4][4] = {};
  const u16* Ap = A + (size_t)(m0 + lr) * KTOT + ko;
  const u16* Bp = Bm + (size_t)(n0 + lr) * KTOT + ko;
  for (int k0 = 0; k0 < KTOT; k0 += 32) {
    bf16x8 af[4], bfr[4];
#pragma unroll
    for (int i = 0; i < 4; ++i) af[i] = *(const bf16x8*)(Ap + (size_t)i * 16 * KTOT + k0);
#pragma unroll
    for (int i = 0; i < 4; ++i) bfr[i] = *(const bf16x8*)(Bp + (size_t)i * 16 * KTOT + k0);
#pragma unroll
    for (int i = 0; i < 4; ++i)
#pragma unroll
      for (int j = 0; j < 4; ++j)
        acc[i][j] = __builtin_amdgcn_mfma_f32_16x16x32_bf16(af[i], bfr[j], acc[i][j], 0, 0, 0);
  }
  int rbase = (l >> 4) * 4;
#pragma unroll
  for (int i = 0; i < 4; ++i) {
#pragma unroll
    for (int j = 0; j < 4; ++j) {
      int gn = n0 + j * 16 + lr;
      float bv = bias[gn];
#pragma unroll
      for (int r = 0; r < 4; ++r) {
        int gm = m0 + i * 16 + rbase + r;
        float v = acc[i][j][r] + bv;
        if (OBF) ((u16*)Cv)[(size_t)gm * N + gn] = f2b(v);
        else     ((float*)Cv)[(size_t)gm * N + gn] = v;
      }
    }
  }
}

// ---------------- enc_proj sub-phase (uses h staged in LDS) ----------------
__device__ __forceinline__ void enc_proj_phase(
    int tid, int gb, int b0, int tt,
    float (*hl)[H_], float (*part)[256],
    const float* __restrict__ attn_W, float* __restrict__ enc_proj)
{
  int b_l = tid >> 6, d_l = (tid >> 2) & 15, kq = tid & 3;
  int d = gb * 16 + d_l;
  const float* wrow = attn_W + (size_t)d * 1024 + 512;  // W_e row
  float acc = 0.f;
#pragma unroll 8
  for (int kk = kq * 128; kk < kq * 128 + 128; kk += 4) {
    float4 wv = *(const float4*)(wrow + kk);
    const float* hp = &hl[b_l][kk];
    acc += wv.x * hp[0] + wv.y * hp[1] + wv.z * hp[2] + wv.w * hp[3];
  }
  part[kq][b_l * 16 + d_l] = acc;
  __syncthreads();
  if (tid < 64) {
    int bl = tid >> 4, dl = tid & 15;
    float s = part[0][bl * 16 + dl] + part[1][bl * 16 + dl] +
              part[2][bl * 16 + dl] + part[3][bl * 16 + dl];
    enc_proj[((size_t)(b0 + bl) * SSRC + tt) * H_ + gb * 16 + dl] = s;
  }
  __syncthreads();
}

// ---------------- persistent recurrence kernel ----------------
// 256 blocks x 256 threads. Group g = blockIdx&7 (32 blocks, 4 batch rows), gb = blockIdx>>3.
__global__ __launch_bounds__(256, 1) void seq_recurrent(
    const float* __restrict__ enc_Whh, const float* __restrict__ attn_W,
    const float* __restrict__ attn_b, const float* __restrict__ attn_v,
    const float* __restrict__ dec_Whh, const float* __restrict__ dec_Wih,
    const u16* __restrict__ encXW, const u16* __restrict__ decXW,
    float* __restrict__ hbuf, float* __restrict__ vpart, float* __restrict__ ctxbuf,
    u16* __restrict__ enc_out_bf, float* __restrict__ enc_proj, u16* __restrict__ dec_h_bf,
    int* __restrict__ bars)
{
  const int tid = threadIdx.x;
  const int blk = blockIdx.x;
  const int g = blk & 7;
  const int gb = blk >> 3;
  const int b0 = g * 4;
  const int ds0 = gb * 16;
  int* flags = bars + g * 64;
  int ep_ = 0;

  __shared__ union {
    float encW[64 * 512];        // f32 [k4][row64][4]
    u16   decW[2][64 * 512];     // bf16 [k8][row64][8], [0]=Whh slice, [1]=Wih_ctx slice
  } W;
  __shared__ float part[4][256];
  __shared__ float zx[4][64];
  __shared__ float smx[4][128];
  __shared__ float scoreS[4][128];
  __shared__ float qS[4][16];
  __shared__ float hl[4][H_];
  __shared__ float cxl[4][H_];
  __shared__ float cS[4][16];
  __shared__ float vS[16];
  __shared__ float bS[16];

  // ---- fill encoder Whh slice (f32), init c state ----
  if (tid < 64) cS[tid >> 4][tid & 15] = 0.f;
  for (int idx = tid; idx < 64 * 512; idx += 256) {
    int row_l = idx >> 9, kk = idx & 511;
    int grow = (row_l >> 4) * 512 + ds0 + (row_l & 15);
    W.encW[(kk >> 2) * 256 + row_l * 4 + (kk & 3)] = enc_Whh[(size_t)grow * 512 + kk];
  }
  __syncthreads();

  // =================== ENCODER ===================
  for (int t = 0; t < SSRC; ++t) {
    const float* hr = hbuf + (t & 1) * (B_ * H_);
    float* hw = hbuf + ((t + 1) & 1) * (B_ * H_);

    // stage h (4 rows) into LDS
    {
      float4* dst = (float4*)&hl[0][0];
      const float4* srcp = (const float4*)(hr + (size_t)b0 * H_);
      for (int i = tid; i < 512; i += 256) dst[i] = srcp[i];
    }
    __syncthreads();

    if (t > 0) enc_proj_phase(tid, gb, b0, t - 1, hl, part, attn_W, enc_proj);

    // z = encXW + h @ Whh^T
    {
      int rl = tid & 63, kq = tid >> 6;
      float acc0 = 0.f, acc1 = 0.f, acc2 = 0.f, acc3 = 0.f;
      int c0 = kq * 32;
#pragma unroll 4
      for (int c = 0; c < 32; ++c) {
        int k4 = c0 + c;
        float4 wv = *(const float4*)&W.encW[k4 * 256 + rl * 4];
        const float* h0p = &hl[0][k4 * 4];
        const float* h1p = &hl[1][k4 * 4];
        const float* h2p = &hl[2][k4 * 4];
        const float* h3p = &hl[3][k4 * 4];
        acc0 += wv.x * h0p[0] + wv.y * h0p[1] + wv.z * h0p[2] + wv.w * h0p[3];
        acc1 += wv.x * h1p[0] + wv.y * h1p[1] + wv.z * h1p[2] + wv.w * h1p[3];
        acc2 += wv.x * h2p[0] + wv.y * h2p[1] + wv.z * h2p[2] + wv.w * h2p[3];
        acc3 += wv.x * h3p[0] + wv.y * h3p[1] + wv.z * h3p[2] + wv.w * h3p[3];
      }
      part[kq][0 * 64 + rl] = acc0;
      part[kq][1 * 64 + rl] = acc1;
      part[kq][2 * 64 + rl] = acc2;
      part[kq][3 * 64 + rl] = acc3;
      __syncthreads();
      {
        int b_l = tid >> 6, rl2 = tid & 63;
        float z = part[0][b_l * 64 + rl2] + part[1][b_l * 64 + rl2] +
                  part[2][b_l * 64 + rl2] + part[3][b_l * 64 + rl2];
        int grow = (rl2 >> 4) * 512 + ds0 + (rl2 & 15);
        z += b2f(encXW[((size_t)(b0 + b_l) * SSRC + t) * G4 + grow]);
        zx[b_l][rl2] = z;
      }
      __syncthreads();
      if (tid < 64) {
        int bl = tid >> 4, jl = tid & 15;
        int b = b0 + bl, j = ds0 + jl;
        float iv = zx[bl][jl], fv = zx[bl][16 + jl], gv = zx[bl][32 + jl], ov = zx[bl][48 + jl];
        float co = cS[bl][jl];
        float cn = sigm(fv) * co + sigm(iv) * tanh_(gv);
        float hn = sigm(ov) * tanh_(cn);
        cS[bl][jl] = cn;
        hw[(size_t)b * H_ + j] = hn;
        enc_out_bf[((size_t)b * SSRC + t) * H_ + j] = f2b(hn);
      }
    }
    gbar(flags, gb, ++ep_);
  }

  // tail: enc_proj for t = 127
  {
    const float* hr = hbuf + (SSRC & 1) * (B_ * H_);
    float4* dst = (float4*)&hl[0][0];
    const float4* srcp = (const float4*)(hr + (size_t)b0 * H_);
    for (int i = tid; i < 512; i += 256) dst[i] = srcp[i];
    __syncthreads();
    enc_proj_phase(tid, gb, b0, SSRC - 1, hl, part, attn_W, enc_proj);
  }

  // ---- refill LDS with decoder weight slices (bf16) + stage attn_v/attn_b slices ----
  __syncthreads();
  for (int idx = tid; idx < 64 * 512; idx += 256) {
    int row_l = idx >> 9, kk = idx & 511;
    int grow = (row_l >> 4) * 512 + ds0 + (row_l & 15);
    W.decW[0][(kk >> 3) * 512 + row_l * 8 + (kk & 7)] = f2b(dec_Whh[(size_t)grow * 512 + kk]);
    W.decW[1][(kk >> 3) * 512 + row_l * 8 + (kk & 7)] = f2b(dec_Wih[(size_t)grow * 768 + 256 + kk]);
  }
  if (tid < 16) { vS[tid] = attn_v[ds0 + tid]; bS[tid] = attn_b[ds0 + tid]; }
  __syncthreads();

  // =================== DECODER ===================
  for (int t = 0; t < STGT; ++t) {
    const float* hr = hbuf + ((SSRC + t) & 1) * (B_ * H_);
    float* hw = hbuf + ((SSRC + t + 1) & 1) * (B_ * H_);

    // ---- Phase A: stage h; q-slice (own 16 d); score partials over own d-slice ----
    {
      float4* dst = (float4*)&hl[0][0];
      const float4* srcp = (const float4*)(hr + (size_t)b0 * H_);
      for (int i = tid; i < 512; i += 256) dst[i] = srcp[i];
    }
    __syncthreads();
    {
      int b_l = tid >> 6, d_l = (tid >> 2) & 15, kq = tid & 3;
      const float* wrow = attn_W + (size_t)(ds0 + d_l) * 1024;  // W_h row
      float acc = 0.f;
#pragma unroll 8
      for (int kk = kq * 128; kk < kq * 128 + 128; kk += 4) {
        float4 wv = *(const float4*)(wrow + kk);
        const float* hp = &hl[b_l][kk];
        acc += wv.x * hp[0] + wv.y * hp[1] + wv.z * hp[2] + wv.w * hp[3];
      }
      part[kq][b_l * 16 + d_l] = acc;
    }
    __syncthreads();
    if (tid < 64) {
      int bl = tid >> 4, dl = tid & 15;
      qS[bl][dl] = part[0][bl * 16 + dl] + part[1][bl * 16 + dl] +
                   part[2][bl * 16 + dl] + part[3][bl * 16 + dl] + bS[dl];
    }
    __syncthreads();
    {
      float* vp = vpart + (size_t)g * 16384 + (size_t)gb * 512;
#pragma unroll
      for (int r = 0; r < 2; ++r) {
        int idx = tid + r * 256;
        int b_l = idx >> 7, s = idx & 127;
        const float* ep = enc_proj + ((size_t)(b0 + b_l) * SSRC + s) * H_ + ds0;
        float acc = 0.f;
#pragma unroll
        for (int dl = 0; dl < 16; dl += 4) {
          float4 e4 = *(const float4*)(ep + dl);
          acc += vS[dl + 0] * tanh_(e4.x + qS[b_l][dl + 0]);
          acc += vS[dl + 1] * tanh_(e4.y + qS[b_l][dl + 1]);
          acc += vS[dl + 2] * tanh_(e4.z + qS[b_l][dl + 2]);
          acc += vS[dl + 3] * tanh_(e4.w + qS[b_l][dl + 3]);
        }
        vp[idx] = acc;
      }
    }
    gbar(flags, gb, ++ep_);

    // ---- Phase B: sum partials -> scores; softmax; context slice ----
    {
      const float* vg = vpart + (size_t)g * 16384;
#pragma unroll
      for (int r = 0; r < 2; ++r) {
        int idx = tid + r * 256;
        int b_l = idx >> 7, s = idx & 127;
        float acc = 0.f;
#pragma unroll 8
        for (int j = 0; j < 32; ++j) acc += vg[(size_t)j * 512 + idx];
        scoreS[b_l][s] = acc;
      }
    }
    __syncthreads();
    {
      int w = tid >> 6, lane = tid & 63;
      float s1 = scoreS[w][lane], s2v = scoreS[w][64 + lane];
      float m = fmaxf(s1, s2v);
      for (int off = 32; off; off >>= 1) m = fmaxf(m, __shfl_xor(m, off));
      float e1 = __expf(s1 - m), e2 = __expf(s2v - m);
      float sm = e1 + e2;
      for (int off = 32; off; off >>= 1) sm += __shfl_xor(sm, off);
      float inv = 1.0f / sm;
      smx[w][lane] = e1 * inv;
      smx[w][64 + lane] = e2 * inv;
    }
    __syncthreads();
    {
      int d_l = tid & 15, b_l = (tid >> 4) & 3, sq = tid >> 6;
      const u16* eo = enc_out_bf + (size_t)(b0 + b_l) * SSRC * H_ + ds0 + d_l;
      float acc = 0.f;
      for (int s = sq * 32; s < sq * 32 + 32; ++s)
        acc += smx[b_l][s] * b2f(eo[(size_t)s * H_]);
      part[sq][b_l * 16 + d_l] = acc;
    }
    __syncthreads();
    if (tid < 64) {
      int bl = tid >> 4, dl = tid & 15;
      ctxbuf[(size_t)(b0 + bl) * H_ + ds0 + dl] =
          part[0][bl * 16 + dl] + part[1][bl * 16 + dl] +
          part[2][bl * 16 + dl] + part[3][bl * 16 + dl];
    }
    gbar(flags, gb, ++ep_);

    // ---- Phase C: z = decXW + h @ Whh^T + ctx @ WihC^T, gates, h/c update ----
    {
      {
        float4* dst = (float4*)&cxl[0][0];
        const float4* srcp = (const float4*)(ctxbuf + (size_t)b0 * H_);
        for (int i = tid; i < 512; i += 256) dst[i] = srcp[i];
      }
      __syncthreads();
      int rl = tid & 63, kq = tid >> 6;
      float acc[4] = {0.f, 0.f, 0.f, 0.f};
#pragma unroll 2
      for (int c = 0; c < 16; ++c) {
        int k8 = kq * 16 + c;
        bf16x8 wv = *(const bf16x8*)&W.decW[0][k8 * 512 + rl * 8];
        float wf0 = b2f((u16)wv[0]), wf1 = b2f((u16)wv[1]), wf2 = b2f((u16)wv[2]), wf3 = b2f((u16)wv[3]);
        float wf4 = b2f((u16)wv[4]), wf5 = b2f((u16)wv[5]), wf6 = b2f((u16)wv[6]), wf7 = b2f((u16)wv[7]);
#pragma unroll
        for (int bl = 0; bl < 4; ++bl) {
          const float* hp = &hl[bl][k8 * 8];
          acc[bl] += wf0 * hp[0] + wf1 * hp[1] + wf2 * hp[2] + wf3 * hp[3] +
                     wf4 * hp[4] + wf5 * hp[5] + wf6 * hp[6] + wf7 * hp[7];
        }
      }
#pragma unroll 2
      for (int c = 0; c < 16; ++c) {
        int k8 = kq * 16 + c;
        bf16x8 wv = *(const bf16x8*)&W.decW[1][k8 * 512 + rl * 8];
        float wf0 = b2f((u16)wv[0]), wf1 = b2f((u16)wv[1]), wf2 = b2f((u16)wv[2]), wf3 = b2f((u16)wv[3]);
        float wf4 = b2f((u16)wv[4]), wf5 = b2f((u16)wv[5]), wf6 = b2f((u16)wv[6]), wf7 = b2f((u16)wv[7]);
#pragma unroll
        for (int bl = 0; bl < 4; ++bl) {
          const float* cp = &cxl[bl][k8 * 8];
          acc[bl] += wf0 * cp[0] + wf1 * cp[1] + wf2 * cp[2] + wf3 * cp[3] +
                     wf4 * cp[4] + wf5 * cp[5] + wf6 * cp[6] + wf7 * cp[7];
        }
      }
      part[kq][0 * 64 + rl] = acc[0];
      part[kq][1 * 64 + rl] = acc[1];
      part[kq][2 * 64 + rl] = acc[2];
      part[kq][3 * 64 + rl] = acc[3];
      __syncthreads();
      {
        int b_l = tid >> 6, rl2 = tid & 63;
        float z = part[0][b_l * 64 + rl2] + part[1][b_l * 64 + rl2] +
                  part[2][b_l * 64 + rl2] + part[3][b_l * 64 + rl2];
        int grow = (rl2 >> 4) * 512 + ds0 + (rl2 & 15);
        z += b2f(decXW[((size_t)(b0 + b_l) * STGT + t) * G4 + grow]);
        zx[b_l][rl2] = z;
      }
      __syncthreads();
      if (tid < 64) {
        int bl = tid >> 4, jl = tid & 15;
        int b = b0 + bl, j = ds0 + jl;
        float iv = zx[bl][jl], fv = zx[bl][16 + jl], gv = zx[bl][32 + jl], ov = zx[bl][48 + jl];
        float co = cS[bl][jl];
        float cn = sigm(fv) * co + sigm(iv) * tanh_(gv);
        float hn = sigm(ov) * tanh_(cn);
        cS[bl][jl] = cn;
        hw[(size_t)b * H_ + j] = hn;
        dec_h_bf[((size_t)b * STGT + t) * H_ + j] = f2b(hn);
      }
    }
    gbar(flags, gb, ++ep_);
  }
}

// ---------------- workspace layout (bytes) ----------------
#define OFF_BAR    0u
#define OFF_H      4096u
#define OFF_AENC   524288u     // A_enc (prep/gemm1), later aliased as vpart (512KB)
#define OFF_ADEC   2621440u    // A_dec (prep/gemm2), later aliased as ctxbuf (64KB)
#define OFF_WIHE   3670016u
#define OFF_WIHD   4718592u
#define OFF_OUTW   5767168u
#define OFF_ENCXW  38535168u
#define OFF_DECXW  55312384u
#define OFF_EOBF   63700992u
#define OFF_EPROJ  67895296u
#define OFF_DECH   76283904u

extern "C" void kernel_launch(void* const* d_in, const int* in_sizes, int n_in,
                              void* d_out, int out_size, void* d_ws, size_t ws_size,
                              hipStream_t stream)
{
  const int*   src     = (const int*)d_in[0];
  const int*   tgt     = (const int*)d_in[1];
  const float* enc_emb = (const float*)d_in[2];
  const float* enc_Wih = (const float*)d_in[3];
  const float* enc_Whh = (const float*)d_in[4];
  const float* enc_b   = (const float*)d_in[5];
  const float* attn_W  = (const float*)d_in[6];
  const float* attn_b  = (const float*)d_in[7];
  const float* attn_v  = (const float*)d_in[8];
  const float* dec_emb = (const float*)d_in[9];
  const float* dec_Wih = (const float*)d_in[10];
  const float* dec_Whh = (const float*)d_in[11];
  const float* dec_b   = (const float*)d_in[12];
  const float* out_W   = (const float*)d_in[13];
  const float* out_b   = (const float*)d_in[14];

  char* ws = (char*)d_ws;
  int*   bars    = (int*)(ws + OFF_BAR);
  float* hbuf    = (float*)(ws + OFF_H);
  u16*   A_enc   = (u16*)(ws + OFF_AENC);
  u16*   A_dec   = (u16*)(ws + OFF_ADEC);
  float* vpart   = (float*)(ws + OFF_AENC);   // alias: dead after gemm1
  float* ctxbuf  = (float*)(ws + OFF_ADEC);   // alias: dead after gemm2
  u16*   WihE    = (u16*)(ws + OFF_WIHE);
  u16*   WihD    = (u16*)(ws + OFF_WIHD);
  u16*   outWb   = (u16*)(ws + OFF_OUTW);
  u16*   encXW   = (u16*)(ws + OFF_ENCXW);
  u16*   decXW   = (u16*)(ws + OFF_DECXW);
  u16*   eobf    = (u16*)(ws + OFF_EOBF);
  float* eproj   = (float*)(ws + OFF_EPROJ);
  u16*   dech    = (u16*)(ws + OFF_DECH);

  // zero barriers + h state (both buffers)
  hipMemsetAsync(d_ws, 0, 135168, stream);

  prep_kernel<<<2048, 256, 0, stream>>>(src, tgt, enc_emb, dec_emb, enc_Wih, dec_Wih, out_W,
                                        A_enc, A_dec, WihE, WihD, outWb);

  // encXW = emb_src @ enc_Wih^T + enc_b   (M=4096, N=2048, K=256) -> bf16
  gemm_nt<256, true><<<512, 256, 0, stream>>>(A_enc, WihE, enc_b, (void*)encXW, 4096, 2048);
  // decXW = emb_tgt @ dec_Wih[:, :E]^T + dec_b  (M=2048, N=2048, K=256) -> bf16
  gemm_nt<256, true><<<256, 256, 0, stream>>>(A_dec, WihD, dec_b, (void*)decXW, 2048, 2048);

  seq_recurrent<<<256, 256, 0, stream>>>(enc_Whh, attn_W, attn_b, attn_v, dec_Whh, dec_Wih,
                                         encXW, decXW, hbuf, vpart, ctxbuf,
                                         eobf, eproj, dech, bars);

  // out = dec_h @ out_W^T + out_b  (M=2048, N=32000, K=512) -> f32
  gemm_nt<512, false><<<4000, 256, 0, stream>>>(dech, outWb, out_b, d_out, 2048, 32000);
}

// Round 3
// 3443.494 us; speedup vs baseline: 2.7818x; 1.6058x over previous
//
#include <hip/hip_runtime.h>

#define B_    32
#define SSRC  128
#define STGT  64
#define E_    256
#define H_    512
#define G4    2048
#define V_    32000

typedef unsigned short u16;
typedef short bf16x8 __attribute__((ext_vector_type(8)));
typedef float f32x4 __attribute__((ext_vector_type(4)));

__device__ __forceinline__ u16 f2b(float f) {
  unsigned u = __float_as_uint(f);
  u += 0x7FFFu + ((u >> 16) & 1u);
  return (u16)(u >> 16);
}
__device__ __forceinline__ float b2f(u16 h) {
  return __uint_as_float(((unsigned)h) << 16);
}
__device__ __forceinline__ float sigm(float x) { return 1.0f / (1.0f + __expf(-x)); }
__device__ __forceinline__ float tanh_(float x) { return 1.0f - 2.0f / (1.0f + __expf(2.0f * x)); }

// Per-access device-coherent load/store (global_load/store with sc0 sc1) —
// bypasses the non-coherent L1/L2 path, NO whole-cache maintenance.
__device__ __forceinline__ void cstore(float* p, float v) {
  __hip_atomic_store(p, v, __ATOMIC_RELAXED, __HIP_MEMORY_SCOPE_AGENT);
}
__device__ __forceinline__ float cload(const float* p) {
  return __hip_atomic_load(p, __ATOMIC_RELAXED, __HIP_MEMORY_SCOPE_AGENT);
}

// ---------------- group barrier: per-block flag + gang poll, NO fences --------
// Ordering: each wave drains its own coherent stores (vmcnt(0)) BEFORE the
// block barrier; then tid0 publishes the arrival flag (coherent store). The
// consumer's data loads are themselves coherent, so no cache invalidate is
// needed on the acquire side.
__device__ __forceinline__ void gbar(int* flags, int myid, int target) {
  asm volatile("s_waitcnt vmcnt(0)" ::: "memory");
  __syncthreads();
  if (threadIdx.x == 0)
    __hip_atomic_store(flags + myid, target, __ATOMIC_RELAXED, __HIP_MEMORY_SCOPE_AGENT);
  if (threadIdx.x < 64) {
    int l = threadIdx.x & 31;
    while (__hip_atomic_load(flags + l, __ATOMIC_RELAXED, __HIP_MEMORY_SCOPE_AGENT) < target)
      __builtin_amdgcn_s_sleep(2);
  }
  __syncthreads();
  asm volatile("" ::: "memory");
}

// ---------------- prep: gathers + bf16 conversions ----------------
__global__ void prep_kernel(const int* __restrict__ src, const int* __restrict__ tgt,
                            const float* __restrict__ enc_emb, const float* __restrict__ dec_emb,
                            const float* __restrict__ enc_Wih, const float* __restrict__ dec_Wih,
                            const float* __restrict__ out_W,
                            u16* __restrict__ A_enc, u16* __restrict__ A_dec,
                            u16* __restrict__ WihE, u16* __restrict__ WihD,
                            u16* __restrict__ outWb)
{
  const long n_outw = (long)V_ * H_;
  const long n_aenc = (long)B_ * SSRC * E_;
  const long n_adec = (long)B_ * STGT * E_;
  const long n_wih  = (long)G4 * E_;
  const long total = n_outw + n_aenc + n_adec + n_wih + n_wih;
  for (long i = (long)blockIdx.x * blockDim.x + threadIdx.x; i < total;
       i += (long)gridDim.x * blockDim.x) {
    long x = i;
    if (x < n_outw) { outWb[x] = f2b(out_W[x]); continue; }
    x -= n_outw;
    if (x < n_aenc) {
      int row = (int)(x >> 8), e = (int)(x & 255);
      A_enc[x] = f2b(enc_emb[(size_t)src[row] * E_ + e]);
      continue;
    }
    x -= n_aenc;
    if (x < n_adec) {
      int row = (int)(x >> 8), e = (int)(x & 255);
      A_dec[x] = f2b(dec_emb[(size_t)tgt[row] * E_ + e]);
      continue;
    }
    x -= n_adec;
    if (x < n_wih) { WihE[x] = f2b(enc_Wih[x]); continue; }
    x -= n_wih;
    {
      int r = (int)(x >> 8), e = (int)(x & 255);
      WihD[x] = f2b(dec_Wih[(size_t)r * 768 + e]);
    }
  }
}

// ---------------- NT GEMM: C[m][n] = sum_k A[m][k]*B[n][k] + bias[n] ----------------
template<int KTOT, bool OBF>
__global__ __launch_bounds__(256, 2) void gemm_nt(
    const u16* __restrict__ A, const u16* __restrict__ Bm,
    const float* __restrict__ bias, void* __restrict__ Cv, int M, int N)
{
  int nbm = M >> 7;
  int bn = blockIdx.x / nbm;
  int bm = blockIdx.x % nbm;
  int w = threadIdx.x >> 6, l = threadIdx.x & 63;
  int wr = w >> 1, wc = w & 1;
  int m0 = bm * 128 + wr * 64, n0 = bn * 128 + wc * 64;
  int lr = l & 15, ko = (l >> 4) * 8;
  f32x4 acc[4][4] = {};
  const u16* Ap = A + (size_t)(m0 + lr) * KTOT + ko;
  const u16* Bp = Bm + (size_t)(n0 + lr) * KTOT + ko;
  for (int k0 = 0; k0 < KTOT; k0 += 32) {
    bf16x8 af[4], bfr[4];
#pragma unroll
    for (int i = 0; i < 4; ++i) af[i] = *(const bf16x8*)(Ap + (size_t)i * 16 * KTOT + k0);
#pragma unroll
    for (int i = 0; i < 4; ++i) bfr[i] = *(const bf16x8*)(Bp + (size_t)i * 16 * KTOT + k0);
#pragma unroll
    for (int i = 0; i < 4; ++i)
#pragma unroll
      for (int j = 0; j < 4; ++j)
        acc[i][j] = __builtin_amdgcn_mfma_f32_16x16x32_bf16(af[i], bfr[j], acc[i][j], 0, 0, 0);
  }
  int rbase = (l >> 4) * 4;
#pragma unroll
  for (int i = 0; i < 4; ++i) {
#pragma unroll
    for (int j = 0; j < 4; ++j) {
      int gn = n0 + j * 16 + lr;
      float bv = bias[gn];
#pragma unroll
      for (int r = 0; r < 4; ++r) {
        int gm = m0 + i * 16 + rbase + r;
        float v = acc[i][j][r] + bv;
        if (OBF) ((u16*)Cv)[(size_t)gm * N + gn] = f2b(v);
        else     ((float*)Cv)[(size_t)gm * N + gn] = v;
      }
    }
  }
}

// ---------------- enc_proj sub-phase (uses h staged in LDS) ----------------
__device__ __forceinline__ void enc_proj_phase(
    int tid, int gb, int b0, int tt,
    float (*hl)[H_], float (*part)[256],
    const float* __restrict__ attn_W, float* __restrict__ enc_proj)
{
  int b_l = tid >> 6, d_l = (tid >> 2) & 15, kq = tid & 3;
  int d = gb * 16 + d_l;
  const float* wrow = attn_W + (size_t)d * 1024 + 512;  // W_e row
  float acc = 0.f;
#pragma unroll 8
  for (int kk = kq * 128; kk < kq * 128 + 128; kk += 4) {
    float4 wv = *(const float4*)(wrow + kk);
    const float* hp = &hl[b_l][kk];
    acc += wv.x * hp[0] + wv.y * hp[1] + wv.z * hp[2] + wv.w * hp[3];
  }
  part[kq][b_l * 16 + d_l] = acc;
  __syncthreads();
  if (tid < 64) {
    int bl = tid >> 4, dl = tid & 15;
    float s = part[0][bl * 16 + dl] + part[1][bl * 16 + dl] +
              part[2][bl * 16 + dl] + part[3][bl * 16 + dl];
    enc_proj[((size_t)(b0 + bl) * SSRC + tt) * H_ + gb * 16 + dl] = s;
  }
  __syncthreads();
}

// ---------------- persistent recurrence kernel ----------------
// 256 blocks x 256 threads. Group g = blockIdx&7 (32 blocks, 4 batch rows), gb = blockIdx>>3.
__global__ __launch_bounds__(256, 1) void seq_recurrent(
    const float* __restrict__ enc_Whh, const float* __restrict__ attn_W,
    const float* __restrict__ attn_b, const float* __restrict__ attn_v,
    const float* __restrict__ dec_Whh, const float* __restrict__ dec_Wih,
    const u16* __restrict__ encXW, const u16* __restrict__ decXW,
    float* __restrict__ hbuf, float* __restrict__ vpart, float* __restrict__ ctxbuf,
    u16* __restrict__ enc_out_bf, float* __restrict__ enc_proj, u16* __restrict__ dec_h_bf,
    int* __restrict__ bars)
{
  const int tid = threadIdx.x;
  const int blk = blockIdx.x;
  const int g = blk & 7;
  const int gb = blk >> 3;
  const int b0 = g * 4;
  const int ds0 = gb * 16;
  int* flags = bars + g * 64;
  int ep_ = 0;

  __shared__ union {
    float encW[64 * 512];        // f32 [k4][row64][4]
    u16   decW[2][64 * 512];     // bf16 [k8][row64][8], [0]=Whh slice, [1]=Wih_ctx slice
  } W;
  __shared__ float part[4][256];
  __shared__ float zx[4][64];
  __shared__ float smx[4][128];
  __shared__ float scoreS[4][128];
  __shared__ float qS[4][16];
  __shared__ float hl[4][H_];
  __shared__ float cxl[4][H_];
  __shared__ float cS[4][16];
  __shared__ float vS[16];
  __shared__ float bS[16];

  // ---- fill encoder Whh slice (f32), init c state ----
  if (tid < 64) cS[tid >> 4][tid & 15] = 0.f;
  for (int idx = tid; idx < 64 * 512; idx += 256) {
    int row_l = idx >> 9, kk = idx & 511;
    int grow = (row_l >> 4) * 512 + ds0 + (row_l & 15);
    W.encW[(kk >> 2) * 256 + row_l * 4 + (kk & 3)] = enc_Whh[(size_t)grow * 512 + kk];
  }
  __syncthreads();

  // =================== ENCODER ===================
  for (int t = 0; t < SSRC; ++t) {
    const float* hr = hbuf + (t & 1) * (B_ * H_);
    float* hw = hbuf + ((t + 1) & 1) * (B_ * H_);

    // stage h (4 rows) into LDS via coherent loads
    {
      float* dst = &hl[0][0];
      const float* srcp = hr + (size_t)b0 * H_;
      for (int i = tid; i < 2048; i += 256) dst[i] = cload(srcp + i);
    }
    __syncthreads();

    if (t > 0) enc_proj_phase(tid, gb, b0, t - 1, hl, part, attn_W, enc_proj);

    // z = encXW + h @ Whh^T
    {
      int rl = tid & 63, kq = tid >> 6;
      float acc0 = 0.f, acc1 = 0.f, acc2 = 0.f, acc3 = 0.f;
      int c0 = kq * 32;
#pragma unroll 4
      for (int c = 0; c < 32; ++c) {
        int k4 = c0 + c;
        float4 wv = *(const float4*)&W.encW[k4 * 256 + rl * 4];
        const float* h0p = &hl[0][k4 * 4];
        const float* h1p = &hl[1][k4 * 4];
        const float* h2p = &hl[2][k4 * 4];
        const float* h3p = &hl[3][k4 * 4];
        acc0 += wv.x * h0p[0] + wv.y * h0p[1] + wv.z * h0p[2] + wv.w * h0p[3];
        acc1 += wv.x * h1p[0] + wv.y * h1p[1] + wv.z * h1p[2] + wv.w * h1p[3];
        acc2 += wv.x * h2p[0] + wv.y * h2p[1] + wv.z * h2p[2] + wv.w * h2p[3];
        acc3 += wv.x * h3p[0] + wv.y * h3p[1] + wv.z * h3p[2] + wv.w * h3p[3];
      }
      part[kq][0 * 64 + rl] = acc0;
      part[kq][1 * 64 + rl] = acc1;
      part[kq][2 * 64 + rl] = acc2;
      part[kq][3 * 64 + rl] = acc3;
      __syncthreads();
      {
        int b_l = tid >> 6, rl2 = tid & 63;
        float z = part[0][b_l * 64 + rl2] + part[1][b_l * 64 + rl2] +
                  part[2][b_l * 64 + rl2] + part[3][b_l * 64 + rl2];
        int grow = (rl2 >> 4) * 512 + ds0 + (rl2 & 15);
        z += b2f(encXW[((size_t)(b0 + b_l) * SSRC + t) * G4 + grow]);
        zx[b_l][rl2] = z;
      }
      __syncthreads();
      if (tid < 64) {
        int bl = tid >> 4, jl = tid & 15;
        int b = b0 + bl, j = ds0 + jl;
        float iv = zx[bl][jl], fv = zx[bl][16 + jl], gv = zx[bl][32 + jl], ov = zx[bl][48 + jl];
        float co = cS[bl][jl];
        float cn = sigm(fv) * co + sigm(iv) * tanh_(gv);
        float hn = sigm(ov) * tanh_(cn);
        cS[bl][jl] = cn;
        cstore(&hw[(size_t)b * H_ + j], hn);
        enc_out_bf[((size_t)b * SSRC + t) * H_ + j] = f2b(hn);
      }
    }
    gbar(flags, gb, ++ep_);
  }

  // tail: enc_proj for t = 127
  {
    const float* hr = hbuf + (SSRC & 1) * (B_ * H_);
    float* dst = &hl[0][0];
    const float* srcp = hr + (size_t)b0 * H_;
    for (int i = tid; i < 2048; i += 256) dst[i] = cload(srcp + i);
    __syncthreads();
    enc_proj_phase(tid, gb, b0, SSRC - 1, hl, part, attn_W, enc_proj);
  }

  // ---- refill LDS with decoder weight slices (bf16) + stage attn_v/attn_b slices ----
  __syncthreads();
  for (int idx = tid; idx < 64 * 512; idx += 256) {
    int row_l = idx >> 9, kk = idx & 511;
    int grow = (row_l >> 4) * 512 + ds0 + (row_l & 15);
    W.decW[0][(kk >> 3) * 512 + row_l * 8 + (kk & 7)] = f2b(dec_Whh[(size_t)grow * 512 + kk]);
    W.decW[1][(kk >> 3) * 512 + row_l * 8 + (kk & 7)] = f2b(dec_Wih[(size_t)grow * 768 + 256 + kk]);
  }
  if (tid < 16) { vS[tid] = attn_v[ds0 + tid]; bS[tid] = attn_b[ds0 + tid]; }
  __syncthreads();

  // =================== DECODER ===================
  for (int t = 0; t < STGT; ++t) {
    const float* hr = hbuf + ((SSRC + t) & 1) * (B_ * H_);
    float* hw = hbuf + ((SSRC + t + 1) & 1) * (B_ * H_);

    // ---- Phase A: stage h; q-slice (own 16 d); score partials over own d-slice ----
    {
      float* dst = &hl[0][0];
      const float* srcp = hr + (size_t)b0 * H_;
      for (int i = tid; i < 2048; i += 256) dst[i] = cload(srcp + i);
    }
    __syncthreads();
    {
      int b_l = tid >> 6, d_l = (tid >> 2) & 15, kq = tid & 3;
      const float* wrow = attn_W + (size_t)(ds0 + d_l) * 1024;  // W_h row
      float acc = 0.f;
#pragma unroll 8
      for (int kk = kq * 128; kk < kq * 128 + 128; kk += 4) {
        float4 wv = *(const float4*)(wrow + kk);
        const float* hp = &hl[b_l][kk];
        acc += wv.x * hp[0] + wv.y * hp[1] + wv.z * hp[2] + wv.w * hp[3];
      }
      part[kq][b_l * 16 + d_l] = acc;
    }
    __syncthreads();
    if (tid < 64) {
      int bl = tid >> 4, dl = tid & 15;
      qS[bl][dl] = part[0][bl * 16 + dl] + part[1][bl * 16 + dl] +
                   part[2][bl * 16 + dl] + part[3][bl * 16 + dl] + bS[dl];
    }
    __syncthreads();
    {
      float* vp = vpart + (size_t)g * 16384 + (size_t)gb * 512;
#pragma unroll
      for (int r = 0; r < 2; ++r) {
        int idx = tid + r * 256;
        int b_l = idx >> 7, s = idx & 127;
        const float* ep = enc_proj + ((size_t)(b0 + b_l) * SSRC + s) * H_ + ds0;
        float acc = 0.f;
#pragma unroll
        for (int dl = 0; dl < 16; dl += 4) {
          float4 e4 = *(const float4*)(ep + dl);
          acc += vS[dl + 0] * tanh_(e4.x + qS[b_l][dl + 0]);
          acc += vS[dl + 1] * tanh_(e4.y + qS[b_l][dl + 1]);
          acc += vS[dl + 2] * tanh_(e4.z + qS[b_l][dl + 2]);
          acc += vS[dl + 3] * tanh_(e4.w + qS[b_l][dl + 3]);
        }
        cstore(vp + idx, acc);
      }
    }
    gbar(flags, gb, ++ep_);

    // ---- Phase B: sum partials -> scores; softmax; context slice ----
    {
      const float* vg = vpart + (size_t)g * 16384;
#pragma unroll
      for (int r = 0; r < 2; ++r) {
        int idx = tid + r * 256;
        int b_l = idx >> 7, s = idx & 127;
        float acc = 0.f;
#pragma unroll 8
        for (int j = 0; j < 32; ++j) acc += cload(vg + (size_t)j * 512 + idx);
        scoreS[b_l][s] = acc;
      }
    }
    __syncthreads();
    {
      int w = tid >> 6, lane = tid & 63;
      float s1 = scoreS[w][lane], s2v = scoreS[w][64 + lane];
      float m = fmaxf(s1, s2v);
      for (int off = 32; off; off >>= 1) m = fmaxf(m, __shfl_xor(m, off));
      float e1 = __expf(s1 - m), e2 = __expf(s2v - m);
      float sm = e1 + e2;
      for (int off = 32; off; off >>= 1) sm += __shfl_xor(sm, off);
      float inv = 1.0f / sm;
      smx[w][lane] = e1 * inv;
      smx[w][64 + lane] = e2 * inv;
    }
    __syncthreads();
    {
      int d_l = tid & 15, b_l = (tid >> 4) & 3, sq = tid >> 6;
      const u16* eo = enc_out_bf + (size_t)(b0 + b_l) * SSRC * H_ + ds0 + d_l;
      float acc = 0.f;
      for (int s = sq * 32; s < sq * 32 + 32; ++s)
        acc += smx[b_l][s] * b2f(eo[(size_t)s * H_]);
      part[sq][b_l * 16 + d_l] = acc;
    }
    __syncthreads();
    if (tid < 64) {
      int bl = tid >> 4, dl = tid & 15;
      cstore(&ctxbuf[(size_t)(b0 + bl) * H_ + ds0 + dl],
             part[0][bl * 16 + dl] + part[1][bl * 16 + dl] +
             part[2][bl * 16 + dl] + part[3][bl * 16 + dl]);
    }
    gbar(flags, gb, ++ep_);

    // ---- Phase C: z = decXW + h @ Whh^T + ctx @ WihC^T, gates, h/c update ----
    {
      {
        float* dst = &cxl[0][0];
        const float* srcp = ctxbuf + (size_t)b0 * H_;
        for (int i = tid; i < 2048; i += 256) dst[i] = cload(srcp + i);
      }
      __syncthreads();
      int rl = tid & 63, kq = tid >> 6;
      float acc[4] = {0.f, 0.f, 0.f, 0.f};
#pragma unroll 2
      for (int c = 0; c < 16; ++c) {
        int k8 = kq * 16 + c;
        bf16x8 wv = *(const bf16x8*)&W.decW[0][k8 * 512 + rl * 8];
        float wf0 = b2f((u16)wv[0]), wf1 = b2f((u16)wv[1]), wf2 = b2f((u16)wv[2]), wf3 = b2f((u16)wv[3]);
        float wf4 = b2f((u16)wv[4]), wf5 = b2f((u16)wv[5]), wf6 = b2f((u16)wv[6]), wf7 = b2f((u16)wv[7]);
#pragma unroll
        for (int bl = 0; bl < 4; ++bl) {
          const float* hp = &hl[bl][k8 * 8];
          acc[bl] += wf0 * hp[0] + wf1 * hp[1] + wf2 * hp[2] + wf3 * hp[3] +
                     wf4 * hp[4] + wf5 * hp[5] + wf6 * hp[6] + wf7 * hp[7];
        }
      }
#pragma unroll 2
      for (int c = 0; c < 16; ++c) {
        int k8 = kq * 16 + c;
        bf16x8 wv = *(const bf16x8*)&W.decW[1][k8 * 512 + rl * 8];
        float wf0 = b2f((u16)wv[0]), wf1 = b2f((u16)wv[1]), wf2 = b2f((u16)wv[2]), wf3 = b2f((u16)wv[3]);
        float wf4 = b2f((u16)wv[4]), wf5 = b2f((u16)wv[5]), wf6 = b2f((u16)wv[6]), wf7 = b2f((u16)wv[7]);
#pragma unroll
        for (int bl = 0; bl < 4; ++bl) {
          const float* cp = &cxl[bl][k8 * 8];
          acc[bl] += wf0 * cp[0] + wf1 * cp[1] + wf2 * cp[2] + wf3 * cp[3] +
                     wf4 * cp[4] + wf5 * cp[5] + wf6 * cp[6] + wf7 * cp[7];
        }
      }
      part[kq][0 * 64 + rl] = acc[0];
      part[kq][1 * 64 + rl] = acc[1];
      part[kq][2 * 64 + rl] = acc[2];
      part[kq][3 * 64 + rl] = acc[3];
      __syncthreads();
      {
        int b_l = tid >> 6, rl2 = tid & 63;
        float z = part[0][b_l * 64 + rl2] + part[1][b_l * 64 + rl2] +
                  part[2][b_l * 64 + rl2] + part[3][b_l * 64 + rl2];
        int grow = (rl2 >> 4) * 512 + ds0 + (rl2 & 15);
        z += b2f(decXW[((size_t)(b0 + b_l) * STGT + t) * G4 + grow]);
        zx[b_l][rl2] = z;
      }
      __syncthreads();
      if (tid < 64) {
        int bl = tid >> 4, jl = tid & 15;
        int b = b0 + bl, j = ds0 + jl;
        float iv = zx[bl][jl], fv = zx[bl][16 + jl], gv = zx[bl][32 + jl], ov = zx[bl][48 + jl];
        float co = cS[bl][jl];
        float cn = sigm(fv) * co + sigm(iv) * tanh_(gv);
        float hn = sigm(ov) * tanh_(cn);
        cS[bl][jl] = cn;
        cstore(&hw[(size_t)b * H_ + j], hn);
        dec_h_bf[((size_t)b * STGT + t) * H_ + j] = f2b(hn);
      }
    }
    gbar(flags, gb, ++ep_);
  }
}

// ---------------- workspace layout (bytes) ----------------
#define OFF_BAR    0u
#define OFF_H      4096u
#define OFF_AENC   524288u     // A_enc (prep/gemm1), later aliased as vpart (512KB)
#define OFF_ADEC   2621440u    // A_dec (prep/gemm2), later aliased as ctxbuf (64KB)
#define OFF_WIHE   3670016u
#define OFF_WIHD   4718592u
#define OFF_OUTW   5767168u
#define OFF_ENCXW  38535168u
#define OFF_DECXW  55312384u
#define OFF_EOBF   63700992u
#define OFF_EPROJ  67895296u
#define OFF_DECH   76283904u

extern "C" void kernel_launch(void* const* d_in, const int* in_sizes, int n_in,
                              void* d_out, int out_size, void* d_ws, size_t ws_size,
                              hipStream_t stream)
{
  const int*   src     = (const int*)d_in[0];
  const int*   tgt     = (const int*)d_in[1];
  const float* enc_emb = (const float*)d_in[2];
  const float* enc_Wih = (const float*)d_in[3];
  const float* enc_Whh = (const float*)d_in[4];
  const float* enc_b   = (const float*)d_in[5];
  const float* attn_W  = (const float*)d_in[6];
  const float* attn_b  = (const float*)d_in[7];
  const float* attn_v  = (const float*)d_in[8];
  const float* dec_emb = (const float*)d_in[9];
  const float* dec_Wih = (const float*)d_in[10];
  const float* dec_Whh = (const float*)d_in[11];
  const float* dec_b   = (const float*)d_in[12];
  const float* out_W   = (const float*)d_in[13];
  const float* out_b   = (const float*)d_in[14];

  char* ws = (char*)d_ws;
  int*   bars    = (int*)(ws + OFF_BAR);
  float* hbuf    = (float*)(ws + OFF_H);
  u16*   A_enc   = (u16*)(ws + OFF_AENC);
  u16*   A_dec   = (u16*)(ws + OFF_ADEC);
  float* vpart   = (float*)(ws + OFF_AENC);   // alias: dead after gemm1
  float* ctxbuf  = (float*)(ws + OFF_ADEC);   // alias: dead after gemm2
  u16*   WihE    = (u16*)(ws + OFF_WIHE);
  u16*   WihD    = (u16*)(ws + OFF_WIHD);
  u16*   outWb   = (u16*)(ws + OFF_OUTW);
  u16*   encXW   = (u16*)(ws + OFF_ENCXW);
  u16*   decXW   = (u16*)(ws + OFF_DECXW);
  u16*   eobf    = (u16*)(ws + OFF_EOBF);
  float* eproj   = (float*)(ws + OFF_EPROJ);
  u16*   dech    = (u16*)(ws + OFF_DECH);

  // zero barriers + h state (both buffers)
  hipMemsetAsync(d_ws, 0, 135168, stream);

  prep_kernel<<<2048, 256, 0, stream>>>(src, tgt, enc_emb, dec_emb, enc_Wih, dec_Wih, out_W,
                                        A_enc, A_dec, WihE, WihD, outWb);

  // encXW = emb_src @ enc_Wih^T + enc_b   (M=4096, N=2048, K=256) -> bf16
  gemm_nt<256, true><<<512, 256, 0, stream>>>(A_enc, WihE, enc_b, (void*)encXW, 4096, 2048);
  // decXW = emb_tgt @ dec_Wih[:, :E]^T + dec_b  (M=2048, N=2048, K=256) -> bf16
  gemm_nt<256, true><<<256, 256, 0, stream>>>(A_dec, WihD, dec_b, (void*)decXW, 2048, 2048);

  seq_recurrent<<<256, 256, 0, stream>>>(enc_Whh, attn_W, attn_b, attn_v, dec_Whh, dec_Wih,
                                         encXW, decXW, hbuf, vpart, ctxbuf,
                                         eobf, eproj, dech, bars);

  // out = dec_h @ out_W^T + out_b  (M=2048, N=32000, K=512) -> f32
  gemm_nt<512, false><<<4000, 256, 0, stream>>>(dech, outWb, out_b, d_out, 2048, 32000);
}